// Round 4
// baseline (18.034 us; speedup 1.0000x reference)
//
#include <hip/hip_runtime.h>

// Problem constants (match reference): B=4, C=64, N=1024, H=8, D=8
#define BATCH 4
#define CH    64
#define NSEQ  1024
// inv_sqrt_d = 1/sqrt(8)
#define INV_SQRT_D 0.35355339059327373f

// Algebraic collapse (verified R0-R2, absmax 0.0):
//   softmax over keys of (q-k)/s == softmax(-k/s)  -> q, Wq dead;
//   out[b,c,n] = o[b,c] for all n,
//   o[b,c] = sum_m exp(-K[b,c,m]/√D) V[b,c,m] / sum_m exp(-K[b,c,m]/√D),
//   K = Wk@x, V = Wv@x. Unstabilized exp safe (K ~ N(0,1)).
//
// R3 (single kernel — R2 showed ~1.2 µs/launch overhead, two kernels lose):
//  - block = (b, c-PAIR): 128 blocks x 1024 threads. Softmax needs full N per
//    block, so c-grouping is the only way to cut the per-block x[b] re-read:
//    L2 traffic 64 MB -> 32 MB (~0.95 µs at 34.5 TB/s aggregate; 128 blocks
//    still span all 8 XCDs so full L2 BW is reachable).
//  - thread owns (c = pair*2 + tid>>9, float2 of n): 64 float2 coalesced
//    global loads, 256 FMA.
//  - weights read from LDS as float4 (32 ds_read_b128, wave-uniform
//    broadcast) instead of 128 ds_read_b32.

__global__ __launch_bounds__(1024)
void global_sub_attn_kernel(const float* __restrict__ x,   // [B,C,N]
                            const float* __restrict__ Wk,  // [C,C]
                            const float* __restrict__ Wv,  // [C,C]
                            float* __restrict__ out)       // [B,C,N]
{
    const int blk   = blockIdx.x;       // b*32 + cpair
    const int b     = blk >> 5;
    const int cpair = blk & 31;
    const int tid   = threadIdx.x;      // 0..1023
    const int g     = tid >> 9;         // 0/1: which c of the pair (wave-uniform)
    const int j     = tid & 511;        // n-pair index: owns n = 2j, 2j+1
    const int lane  = tid & 63;
    const int wave  = tid >> 6;         // 0..15 (waves 0-7: g=0, 8-15: g=1)

    __shared__ __align__(16) float wk_s[2][CH];
    __shared__ __align__(16) float wv_s[2][CH];
    __shared__ float red_a[16];
    __shared__ float red_b[16];

    if (tid < 256) {
        const int gg = (tid >> 6) & 1;
        const int cp = tid & 63;
        const int cc = cpair * 2 + gg;
        if (tid < 128) wk_s[gg][cp] = Wk[cc * CH + cp];
        else           wv_s[gg][cp] = Wv[cc * CH + cp];
    }
    __syncthreads();

    // ---- projections K,V at n0=2j, n1=2j+1 for channel c = cpair*2+g ----
    const float* xb = x + (size_t)b * CH * NSEQ + 2 * j;
    float k0 = 0.f, k1 = 0.f, v0 = 0.f, v1 = 0.f;

    #pragma unroll 4
    for (int cp4 = 0; cp4 < CH; cp4 += 4) {
        const float4 wk4 = *reinterpret_cast<const float4*>(&wk_s[g][cp4]);
        const float4 wv4 = *reinterpret_cast<const float4*>(&wv_s[g][cp4]);
        const float2 x0 = *reinterpret_cast<const float2*>(xb + (cp4 + 0) * NSEQ);
        const float2 x1 = *reinterpret_cast<const float2*>(xb + (cp4 + 1) * NSEQ);
        const float2 x2 = *reinterpret_cast<const float2*>(xb + (cp4 + 2) * NSEQ);
        const float2 x3 = *reinterpret_cast<const float2*>(xb + (cp4 + 3) * NSEQ);
        k0 = fmaf(wk4.x, x0.x, k0); k1 = fmaf(wk4.x, x0.y, k1);
        v0 = fmaf(wv4.x, x0.x, v0); v1 = fmaf(wv4.x, x0.y, v1);
        k0 = fmaf(wk4.y, x1.x, k0); k1 = fmaf(wk4.y, x1.y, k1);
        v0 = fmaf(wv4.y, x1.x, v0); v1 = fmaf(wv4.y, x1.y, v1);
        k0 = fmaf(wk4.z, x2.x, k0); k1 = fmaf(wk4.z, x2.y, k1);
        v0 = fmaf(wv4.z, x2.x, v0); v1 = fmaf(wv4.z, x2.y, v1);
        k0 = fmaf(wk4.w, x3.x, k0); k1 = fmaf(wk4.w, x3.y, k1);
        v0 = fmaf(wv4.w, x3.x, v0); v1 = fmaf(wv4.w, x3.y, v1);
    }

    // ---- unstabilized softmax partials ----
    const float e0 = __expf(-k0 * INV_SQRT_D);
    const float e1 = __expf(-k1 * INV_SQRT_D);
    float se  = e0 + e1;
    float sev = e0 * v0 + e1 * v1;

    #pragma unroll
    for (int off = 32; off > 0; off >>= 1) {
        se  += __shfl_xor(se,  off);
        sev += __shfl_xor(sev, off);
    }
    if (lane == 0) { red_a[wave] = se; red_b[wave] = sev; }
    __syncthreads();

    // each thread sums its group's 8 wave partials (LDS broadcast reads)
    float tse = 0.f, tsev = 0.f;
    #pragma unroll
    for (int w = 0; w < 8; ++w) { tse += red_a[g * 8 + w]; tsev += red_b[g * 8 + w]; }
    const float o = tsev / tse;

    // ---- broadcast scalar to the whole [b,c,:] row (float2 per thread) ----
    const int c = cpair * 2 + g;
    float2 ov; ov.x = o; ov.y = o;
    *reinterpret_cast<float2*>(out + ((size_t)b * CH + c) * NSEQ + 2 * j) = ov;
}

extern "C" void kernel_launch(void* const* d_in, const int* in_sizes, int n_in,
                              void* d_out, int out_size, void* d_ws, size_t ws_size,
                              hipStream_t stream) {
    const float* x  = (const float*)d_in[0];
    // d_in[1] = Wq — dead (softmax over keys cancels q); never read.
    const float* Wk = (const float*)d_in[2];
    const float* Wv = (const float*)d_in[3];
    float* out = (float*)d_out;

    global_sub_attn_kernel<<<BATCH * (CH / 2), 1024, 0, stream>>>(x, Wk, Wv, out);
}

// Round 5
// 10.059 us; speedup vs baseline: 1.7927x; 1.7927x over previous
//
#include <hip/hip_runtime.h>

// Problem constants (match reference): B=4, C=64, N=1024, H=8, D=8
#define BATCH 4
#define CH    64
#define NSEQ  1024
// inv_sqrt_d = 1/sqrt(8)
#define INV_SQRT_D 0.35355339059327373f

// Algebraic collapse (verified R0-R3, absmax 0.0):
//   softmax over keys of (q-k)/s == softmax(-k/s)  -> q, Wq dead;
//   out[b,c,n] = o[b,c] for all n,
//   o[b,c] = sum_m exp(-K[b,c,m]/sqrt(D)) V[b,c,m] / sum_m exp(-K[b,c,m]/sqrt(D)),
//   K = Wk@x, V = Wv@x. Unstabilized exp safe (K ~ N(0,1), |score| ~< 2).
//
// Structure history: R1 (256 blk x 1024 thr, scalar loads) = 10.2 us (best).
// R2 two-kernel split: +launch overhead, lost. R3 c-pair grouping at 128
// blocks: halved active CUs, same per-CU L2 bytes, 2x per-CU compute -> 18 us.
// => keep 256 blocks on 256 CUs; optimize within the block.
//
// R4: 2-D split inside the block. s=tid>>8 owns a 16-channel slice of cp,
// jj=tid&255 owns 4 consecutive n. Each thread: 16 float4 x-loads (1 KB/wave
// per instr vs R1's 256 B) + 128 FMA -> partial K/V float4 into LDS ->
// barrier -> remap one n per thread, sum 4 partials, then the proven R1
// reduction tail. Same bytes, 1/4 the VMEM instructions.

__global__ __launch_bounds__(1024)
void global_sub_attn_kernel(const float* __restrict__ x,   // [B,C,N]
                            const float* __restrict__ Wk,  // [C,C]
                            const float* __restrict__ Wv,  // [C,C]
                            float* __restrict__ out)       // [B,C,N]
{
    const int bc   = blockIdx.x;       // b*64 + c
    const int b    = bc >> 6;
    const int c    = bc & 63;
    const int tid  = threadIdx.x;      // 0..1023
    const int s    = tid >> 8;         // 0..3: cp-slice (16 channels)
    const int jj   = tid & 255;        // owns n = 4*jj .. 4*jj+3
    const int lane = tid & 63;
    const int wave = tid >> 6;         // 0..15

    __shared__ float wk_s[CH];
    __shared__ float wv_s[CH];
    __shared__ __align__(16) float kp[4][NSEQ];   // partial K per cp-slice
    __shared__ __align__(16) float vp[4][NSEQ];   // partial V per cp-slice
    __shared__ float red_a[16];
    __shared__ float red_b[16];

    if (tid < CH)          wk_s[tid]      = Wk[c * CH + tid];
    else if (tid < 2 * CH) wv_s[tid - CH] = Wv[c * CH + (tid - CH)];
    __syncthreads();

    // ---- phase 1: partial projections over this thread's 16-channel slice ----
    const float* xb = x + (size_t)b * CH * NSEQ + 4 * jj;
    float4 ka = make_float4(0.f, 0.f, 0.f, 0.f);
    float4 va = make_float4(0.f, 0.f, 0.f, 0.f);
    const int cp0 = s * 16;
    #pragma unroll
    for (int i = 0; i < 16; ++i) {
        const int cp = cp0 + i;
        const float4 xv = *reinterpret_cast<const float4*>(xb + cp * NSEQ);
        const float wk = wk_s[cp];
        const float wv = wv_s[cp];
        ka.x = fmaf(wk, xv.x, ka.x); ka.y = fmaf(wk, xv.y, ka.y);
        ka.z = fmaf(wk, xv.z, ka.z); ka.w = fmaf(wk, xv.w, ka.w);
        va.x = fmaf(wv, xv.x, va.x); va.y = fmaf(wv, xv.y, va.y);
        va.z = fmaf(wv, xv.z, va.z); va.w = fmaf(wv, xv.w, va.w);
    }
    *reinterpret_cast<float4*>(&kp[s][4 * jj]) = ka;
    *reinterpret_cast<float4*>(&vp[s][4 * jj]) = va;
    __syncthreads();

    // ---- phase 2: remap, one n per thread; combine the 4 cp-slices ----
    const int n = tid;
    const float kacc = ((kp[0][n] + kp[1][n]) + (kp[2][n] + kp[3][n]));
    const float vacc = ((vp[0][n] + vp[1][n]) + (vp[2][n] + vp[3][n]));

    const float e  = __expf(-kacc * INV_SQRT_D);
    float se  = e;
    float sev = e * vacc;

    #pragma unroll
    for (int off = 32; off > 0; off >>= 1) {
        se  += __shfl_xor(se,  off);
        sev += __shfl_xor(sev, off);
    }
    if (lane == 0) { red_a[wave] = se; red_b[wave] = sev; }
    __syncthreads();

    float tse = 0.f, tsev = 0.f;
    #pragma unroll
    for (int w = 0; w < 16; ++w) { tse += red_a[w]; tsev += red_b[w]; }

    out[(size_t)bc * NSEQ + n] = tsev / tse;
}

extern "C" void kernel_launch(void* const* d_in, const int* in_sizes, int n_in,
                              void* d_out, int out_size, void* d_ws, size_t ws_size,
                              hipStream_t stream) {
    const float* x  = (const float*)d_in[0];
    // d_in[1] = Wq — dead (softmax over keys cancels q); never read.
    const float* Wk = (const float*)d_in[2];
    const float* Wv = (const float*)d_in[3];
    float* out = (float*)d_out;

    global_sub_attn_kernel<<<BATCH * CH, 1024, 0, stream>>>(x, Wk, Wv, out);
}